// Round 3
// baseline (395.783 us; speedup 1.0000x reference)
//
#include <hip/hip_runtime.h>
#include <hip/hip_bf16.h>
#include <math.h>

// MoE noisy-top1 gating:
//   clean = input @ w_gate            [N,3]
//   raw   = input @ w_noise           [N,3]
//   std   = softplus(raw) + 0.2
//   logit = clean + noise * std
//   out   = argmax_e(logit)  (int32, lowest index on ties)
//
// N=262144 tokens, D=256, E=3. Memory-bound floor ~43 us (272 MB @ 6.3 TB/s).
//
// R1: one wave/token, 36 dependent shuffles/token -> 216 us (latency-bound).
// R2: 8 lanes/token, 3-step butterfly over 8 tokens -> ~140 us, but weight
//     loads sat inside the group loop: 192 weight vmem instr/wave = 6 MiB of
//     L1 traffic per CU for 6 KiB of weights.
// R3: loop inversion — pass (p) outer, token-group inner. Weights for (p,s)
//     loaded ONCE per wave (48 instr instead of 192) and held in registers
//     while 32 tokens consume them. Accumulators acc[4][6] in VGPRs.

#define NTOK 262144
#define DDIM 256
#define NEXP 3
#define NOISE_EPS 0.2f

__device__ __forceinline__ float softplus_stable(float x) {
    // log(1+exp(x)) = max(x,0) + log1p(exp(-|x|))   (matches jax.nn.softplus)
    return fmaxf(x, 0.0f) + log1pf(expf(-fabsf(x)));
}

__global__ __launch_bounds__(256) void moe_gate_kernel(
    const float* __restrict__ input,    // [N, D]
    const float* __restrict__ w_gate,   // [D, E] row-major
    const float* __restrict__ w_noise,  // [D, E] row-major
    const float* __restrict__ noise,    // [N, E]
    int* __restrict__ out)              // [N]
{
    const int lane = threadIdx.x & 63;
    const int s    = lane & 7;    // sublane within token: dims 32p+4s..+3
    const int g    = lane >> 3;   // token slot within wave (8 tokens concurrent)

    const int wavesPerBlk = blockDim.x >> 6;
    const int waveId      = blockIdx.x * wavesPerBlk + (threadIdx.x >> 6);

    // 8192 waves x 32 tokens = 262144. 4 groups of 8 tokens per wave.
    const int tBase = waveId * 32;

    const float4* in4 = (const float4*)input;   // row = 64 float4s
    const float4* wg4 = (const float4*)w_gate;  // [D*E/4] = 192 float4s
    const float4* wn4 = (const float4*)w_noise;

    // acc[grp][0..2] = gate experts, acc[grp][3..5] = noise experts
    float aG0[4] = {0.f, 0.f, 0.f, 0.f};
    float aG1[4] = {0.f, 0.f, 0.f, 0.f};
    float aG2[4] = {0.f, 0.f, 0.f, 0.f};
    float aN0[4] = {0.f, 0.f, 0.f, 0.f};
    float aN1[4] = {0.f, 0.f, 0.f, 0.f};
    float aN2[4] = {0.f, 0.f, 0.f, 0.f};

    #pragma unroll
    for (int p = 0; p < 8; ++p) {
        // Weights for this lane's 4 dims of pass p: 12 contiguous floats at
        // float4 index 3*(8p+s). Loaded once, reused by all 4 token groups.
        const int wi = 3 * (p * 8 + s);
        const float4 wg0 = wg4[wi + 0];  // {d0e0 d0e1 d0e2 d1e0}
        const float4 wg1 = wg4[wi + 1];  // {d1e1 d1e2 d2e0 d2e1}
        const float4 wg2 = wg4[wi + 2];  // {d2e2 d3e0 d3e1 d3e2}
        const float4 wn0 = wn4[wi + 0];
        const float4 wn1 = wn4[wi + 1];
        const float4 wn2 = wn4[wi + 2];

        #pragma unroll
        for (int grp = 0; grp < 4; ++grp) {
            const int t = tBase + grp * 8 + g;
            const float4 x = in4[(size_t)t * 64 + p * 8 + s];

            aG0[grp] = fmaf(x.x, wg0.x, fmaf(x.y, wg0.w, fmaf(x.z, wg1.z, fmaf(x.w, wg2.y, aG0[grp]))));
            aG1[grp] = fmaf(x.x, wg0.y, fmaf(x.y, wg1.x, fmaf(x.z, wg1.w, fmaf(x.w, wg2.z, aG1[grp]))));
            aG2[grp] = fmaf(x.x, wg0.z, fmaf(x.y, wg1.y, fmaf(x.z, wg2.x, fmaf(x.w, wg2.w, aG2[grp]))));
            aN0[grp] = fmaf(x.x, wn0.x, fmaf(x.y, wn0.w, fmaf(x.z, wn1.z, fmaf(x.w, wn2.y, aN0[grp]))));
            aN1[grp] = fmaf(x.x, wn0.y, fmaf(x.y, wn1.x, fmaf(x.z, wn1.w, fmaf(x.w, wn2.z, aN1[grp]))));
            aN2[grp] = fmaf(x.x, wn0.z, fmaf(x.y, wn1.y, fmaf(x.z, wn2.x, fmaf(x.w, wn2.w, aN2[grp]))));
        }
    }

    #pragma unroll
    for (int grp = 0; grp < 4; ++grp) {
        const int t = tBase + grp * 8 + g;

        float g0 = aG0[grp], g1 = aG1[grp], g2 = aG2[grp];
        float n0 = aN0[grp], n1 = aN1[grp], n2 = aN2[grp];

        // Reduce across the 8 sublanes of each token group (3 butterfly steps,
        // all 8 tokens of the wave reduced simultaneously). Every lane ends up
        // holding the full sums for its token.
        #pragma unroll
        for (int st = 1; st < 8; st <<= 1) {
            g0 += __shfl_xor(g0, st);
            g1 += __shfl_xor(g1, st);
            g2 += __shfl_xor(g2, st);
            n0 += __shfl_xor(n0, st);
            n1 += __shfl_xor(n1, st);
            n2 += __shfl_xor(n2, st);
        }

        // Epilogue: all lanes of the group compute (no divergence); s==0 stores.
        const float* nz = noise + (size_t)t * NEXP;
        const float l0 = fmaf(nz[0], softplus_stable(n0) + NOISE_EPS, g0);
        const float l1 = fmaf(nz[1], softplus_stable(n1) + NOISE_EPS, g1);
        const float l2 = fmaf(nz[2], softplus_stable(n2) + NOISE_EPS, g2);

        int best = 0;
        float bv = l0;
        if (l1 > bv) { bv = l1; best = 1; }
        if (l2 > bv) { bv = l2; best = 2; }
        if (s == 0) out[t] = best;
    }
}

extern "C" void kernel_launch(void* const* d_in, const int* in_sizes, int n_in,
                              void* d_out, int out_size, void* d_ws, size_t ws_size,
                              hipStream_t stream) {
    const float* input   = (const float*)d_in[0];
    const float* w_gate  = (const float*)d_in[1];
    const float* w_noise = (const float*)d_in[2];
    const float* noise   = (const float*)d_in[3];
    int* out = (int*)d_out;

    // 2048 blocks x 256 thr = 8192 waves -> 32 tokens/wave; 8 blocks/CU.
    dim3 grid(2048), block(256);
    moe_gate_kernel<<<grid, block, 0, stream>>>(input, w_gate, w_noise, noise, out);
}

// Round 4
// 361.692 us; speedup vs baseline: 1.0943x; 1.0943x over previous
//
#include <hip/hip_runtime.h>
#include <hip/hip_bf16.h>
#include <math.h>

// MoE noisy-top1 gating:
//   clean = input @ w_gate            [N,3]
//   raw   = input @ w_noise           [N,3]
//   std   = softplus(raw) + 0.2
//   logit = clean + noise * std
//   out   = argmax_e(logit)  (int32, lowest index on ties)
//
// N=262144 tokens, D=256, E=3. Memory-bound floor ~43 us (272 MB @ 6.3 TB/s).
//
// R1: one wave/token, 64-lane butterflies -> 216 us (VALU/latency bound).
// R2: 8 lanes/token, 3-step butterfly -> ~140 us.
// R3: hoisted weight loads out of the token loop -> NEUTRAL (~145 us).
//     Conclusion: weight L1 traffic was never the bottleneck; the kernel is
//     vmem-wait serialized (only 4 KB in flight per vmcnt drain, 8 drains
//     per wave, weight loads polluting the in-order vmcnt stream).
// R4: (a) 8 tokens/wave, whole row tile (8 float4/lane) preloaded upfront ->
//     8 KB in flight, ONE vmcnt drain per wave; (b) weights staged to LDS
//     once per block -> FMA loop uses ds_read (lgkmcnt, independent of
//     vmcnt), conflict-free layout; (c) math order bitwise identical to R2/R3.

#define NTOK 262144
#define DDIM 256
#define NEXP 3
#define NOISE_EPS 0.2f

__device__ __forceinline__ float softplus_stable(float x) {
    // log(1+exp(x)) = max(x,0) + log1p(exp(-|x|))   (matches jax.nn.softplus)
    return fmaxf(x, 0.0f) + log1pf(expf(-fabsf(x)));
}

__global__ __launch_bounds__(256) void moe_gate_kernel(
    const float* __restrict__ input,    // [N, D]
    const float* __restrict__ w_gate,   // [D, E] row-major
    const float* __restrict__ w_noise,  // [D, E] row-major
    const float* __restrict__ noise,    // [N, E]
    int* __restrict__ out)              // [N]
{
    // Weights in LDS: 192 float4 each (D*E = 768 floats), 6 KB total.
    __shared__ float4 sWg[192];
    __shared__ float4 sWn[192];

    const int tid = threadIdx.x;
    const float4* wg4 = (const float4*)w_gate;
    const float4* wn4 = (const float4*)w_noise;
    if (tid < 192) {
        sWg[tid] = wg4[tid];
        sWn[tid] = wn4[tid];
    }
    __syncthreads();

    const int lane = tid & 63;
    const int s    = lane & 7;    // sublane within token: dims 32p+4s..+3
    const int g    = lane >> 3;   // token slot within wave (8 tokens/wave)

    const int waveId = blockIdx.x * 4 + (tid >> 6);
    const int t      = waveId * 8 + g;          // this lane's token

    // Preload the entire row tile: 8 float4s (dims 32p+4s..+3 for p=0..7).
    // All 8 loads issued back-to-back -> 8 KB/wave in flight, one drain.
    const float4* in4  = (const float4*)input;
    const float4* rowp = in4 + (size_t)t * 64 + s;
    float4 x[8];
    #pragma unroll
    for (int p = 0; p < 8; ++p) x[p] = rowp[p * 8];

    // Prefetch noise early too (3 floats, tiny).
    const float* nz = noise + (size_t)t * NEXP;
    const float nz0 = nz[0], nz1 = nz[1], nz2 = nz[2];

    float g0 = 0.f, g1 = 0.f, g2 = 0.f;
    float n0 = 0.f, n1 = 0.f, n2 = 0.f;

    #pragma unroll
    for (int p = 0; p < 8; ++p) {
        // Weights for this lane's 4 dims of pass p (LDS, conflict-free:
        // 8 unique addresses spanning all 32 banks, 8-lane broadcast each).
        const int wi = 3 * (p * 8 + s);
        const float4 wg0 = sWg[wi + 0];  // {d0e0 d0e1 d0e2 d1e0}
        const float4 wg1 = sWg[wi + 1];  // {d1e1 d1e2 d2e0 d2e1}
        const float4 wg2 = sWg[wi + 2];  // {d2e2 d3e0 d3e1 d3e2}
        const float4 wn0 = sWn[wi + 0];
        const float4 wn1 = sWn[wi + 1];
        const float4 wn2 = sWn[wi + 2];

        // Identical FMA nesting and p-ascending order as R2/R3 (bitwise same).
        g0 = fmaf(x[p].x, wg0.x, fmaf(x[p].y, wg0.w, fmaf(x[p].z, wg1.z, fmaf(x[p].w, wg2.y, g0))));
        g1 = fmaf(x[p].x, wg0.y, fmaf(x[p].y, wg1.x, fmaf(x[p].z, wg1.w, fmaf(x[p].w, wg2.z, g1))));
        g2 = fmaf(x[p].x, wg0.z, fmaf(x[p].y, wg1.y, fmaf(x[p].z, wg2.x, fmaf(x[p].w, wg2.w, g2))));
        n0 = fmaf(x[p].x, wn0.x, fmaf(x[p].y, wn0.w, fmaf(x[p].z, wn1.z, fmaf(x[p].w, wn2.y, n0))));
        n1 = fmaf(x[p].x, wn0.y, fmaf(x[p].y, wn1.x, fmaf(x[p].z, wn1.w, fmaf(x[p].w, wn2.z, n1))));
        n2 = fmaf(x[p].x, wn0.z, fmaf(x[p].y, wn1.y, fmaf(x[p].z, wn2.x, fmaf(x[p].w, wn2.w, n2))));
    }

    // Reduce across the 8 sublanes of each token (3 butterfly steps, all 8
    // tokens of the wave simultaneously). Same tree as R2/R3.
    #pragma unroll
    for (int st = 1; st < 8; st <<= 1) {
        g0 += __shfl_xor(g0, st);
        g1 += __shfl_xor(g1, st);
        g2 += __shfl_xor(g2, st);
        n0 += __shfl_xor(n0, st);
        n1 += __shfl_xor(n1, st);
        n2 += __shfl_xor(n2, st);
    }

    // Epilogue: all lanes compute (no divergence); s==0 stores.
    const float l0 = fmaf(nz0, softplus_stable(n0) + NOISE_EPS, g0);
    const float l1 = fmaf(nz1, softplus_stable(n1) + NOISE_EPS, g1);
    const float l2 = fmaf(nz2, softplus_stable(n2) + NOISE_EPS, g2);

    int best = 0;
    float bv = l0;
    if (l1 > bv) { bv = l1; best = 1; }
    if (l2 > bv) { bv = l2; best = 2; }
    if (s == 0) out[t] = best;
}

extern "C" void kernel_launch(void* const* d_in, const int* in_sizes, int n_in,
                              void* d_out, int out_size, void* d_ws, size_t ws_size,
                              hipStream_t stream) {
    const float* input   = (const float*)d_in[0];
    const float* w_gate  = (const float*)d_in[1];
    const float* w_noise = (const float*)d_in[2];
    const float* noise   = (const float*)d_in[3];
    int* out = (int*)d_out;

    // 8192 blocks x 256 thr = 32768 waves x 8 tokens = 262144.
    dim3 grid(8192), block(256);
    moe_gate_kernel<<<grid, block, 0, stream>>>(input, w_gate, w_noise, noise, out);
}